// Round 1
// 2761.925 us; speedup vs baseline: 1.3500x; 1.3500x over previous
//
#include <hip/hip_runtime.h>
#include <math.h>

#define BB 8192
#define KK 32
#define DD 768
#define HH 256
#define RR 32
#define SS 4

typedef unsigned short u16;
typedef unsigned int   u32;
typedef __attribute__((ext_vector_type(8))) short short8v;  // 8 bf16 (4 VGPRs)
typedef __attribute__((ext_vector_type(4))) float f32x4;

// ---------------- helpers ----------------
__device__ __forceinline__ float blk_sum256(float v, float* redw) {
  #pragma unroll
  for (int off = 32; off > 0; off >>= 1) v += __shfl_down(v, off, 64);
  __syncthreads();
  if ((threadIdx.x & 63) == 0) redw[threadIdx.x >> 6] = v;
  __syncthreads();
  return redw[0] + redw[1] + redw[2] + redw[3];
}

__device__ __forceinline__ u16 f2bf_rne(float f) {
  const u32 u = __float_as_uint(f);
  return (u16)((u + 0x7fffu + ((u >> 16) & 1u)) >> 16);
}

// ---------------- weight split: fp32 -> bf16 hi/lo ----------------
__global__ __launch_bounds__(256) void split_kernel(
    const float* __restrict__ W, u16* __restrict__ hi, u16* __restrict__ lo, int total)
{
  const int i = blockIdx.x * 256 + threadIdx.x;
  if (i < total) {
    const float f = W[i];
    const u32 u = __float_as_uint(f);
    hi[i] = (u16)(u >> 16);                       // truncate; lo captures remainder
    const float l = f - __uint_as_float(u & 0xffff0000u);
    lo[i] = f2bf_rne(l);
  }
}

// transpose-split: W[Rr][Cc] -> out[Cc][Rr] bf16 hi/lo
__global__ __launch_bounds__(256) void tsplit_kernel(
    const float* __restrict__ W, u16* __restrict__ hi, u16* __restrict__ lo, int Rr, int Cc)
{
  const int o = blockIdx.x * 256 + threadIdx.x;
  if (o < Rr * Cc) {
    const int c = o / Rr, r = o % Rr;
    const float f = W[(size_t)r * Cc + c];
    const u32 u = __float_as_uint(f);
    hi[o] = (u16)(u >> 16);
    const float l = f - __uint_as_float(u & 0xffff0000u);
    lo[o] = f2bf_rne(l);
  }
}

// ---------------- split-bf16 MFMA GEMM ----------------
// C[M,N] = A(fp32)[M,Kd] @ W^T  (W pre-split into bf16 hi/lo, layout [N][Kd])
// + optional bias[n] + optional addm[m,n].
// 3-term split: A_hi*W_hi + A_hi*W_lo + A_lo*W_hi  (err ~2^-17 rel)
// BM=BN=128, BK=32, 256 thr = 4 waves (2x2), wave tile 64x64, 4x4 frags 16x16x32.
// LDS row stride 40 bf16 = 80B: 16B-aligned b128, uniform bank spread.
#define LSR 40
__global__ __launch_bounds__(256) void gemm_mfma(
    const float* __restrict__ A, const u16* __restrict__ Whi, const u16* __restrict__ Wlo,
    const float* __restrict__ bias, const float* __restrict__ addm,
    float* __restrict__ C, int M, int N, int Kd)
{
  __shared__ __align__(16) u16 Ah[128 * LSR];
  __shared__ __align__(16) u16 Al[128 * LSR];
  __shared__ __align__(16) u16 Bh[128 * LSR];
  __shared__ __align__(16) u16 Bl[128 * LSR];

  const int tid = threadIdx.x;
  // bijective XCD swizzle (all grids here have nwg % 8 == 0):
  // consecutive-in-time blocks on one XCD get consecutive tile ordinals ->
  // the 2 N-blocks sharing an A panel hit the same L2.
  const int nbx = gridDim.x;
  const int nwg = nbx * gridDim.y;
  const int orig = blockIdx.y * nbx + blockIdx.x;
  const int wg = (orig & 7) * (nwg >> 3) + (orig >> 3);
  const int n0 = (wg % nbx) * 128;
  const int m0 = (wg / nbx) * 128;

  // staging role: thread t -> row t>>1 (of 128), k-quarter (t&1)*16
  const int srow = tid >> 1;
  const int skq  = (tid & 1) << 4;
  const float* aptr = &A[(size_t)(m0 + srow) * Kd + skq];
  const u16* whp = &Whi[(size_t)(n0 + srow) * Kd + skq];
  const u16* wlp = &Wlo[(size_t)(n0 + srow) * Kd + skq];
  const int sA = srow * LSR + skq;   // u16 index into LDS tiles

  // compute role
  const int lane = tid & 63;
  const int w  = tid >> 6;
  const int wm = (w >> 1) << 6;      // wave M offset: 0/64
  const int wn = (w & 1) << 6;       // wave N offset: 0/64
  const int lr = lane & 15;
  const int g8 = (lane >> 4) << 3;   // k sub-offset 0/8/16/24

  f32x4 acc[4][4] = {};

  for (int k0 = 0; k0 < Kd; k0 += 32) {
    // ---- stage A (convert fp32 -> hi/lo bf16) ----
    float f[16];
    *(float4*)&f[0]  = *(const float4*)(aptr);
    *(float4*)&f[4]  = *(const float4*)(aptr + 4);
    *(float4*)&f[8]  = *(const float4*)(aptr + 8);
    *(float4*)&f[12] = *(const float4*)(aptr + 12);
    aptr += 32;
    u32 hp[8], lp[8];
    #pragma unroll
    for (int i = 0; i < 8; i++) {
      const u32 u0 = __float_as_uint(f[2*i]);
      const u32 u1 = __float_as_uint(f[2*i+1]);
      hp[i] = (u0 >> 16) | (u1 & 0xffff0000u);
      const float l0 = f[2*i]   - __uint_as_float(u0 & 0xffff0000u);
      const float l1 = f[2*i+1] - __uint_as_float(u1 & 0xffff0000u);
      lp[i] = (u32)f2bf_rne(l0) | ((u32)f2bf_rne(l1) << 16);
    }
    *(uint4*)&Ah[sA]     = make_uint4(hp[0], hp[1], hp[2], hp[3]);
    *(uint4*)&Ah[sA + 8] = make_uint4(hp[4], hp[5], hp[6], hp[7]);
    *(uint4*)&Al[sA]     = make_uint4(lp[0], lp[1], lp[2], lp[3]);
    *(uint4*)&Al[sA + 8] = make_uint4(lp[4], lp[5], lp[6], lp[7]);
    // ---- stage B (already bf16 in global) ----
    {
      const uint4 b0 = *(const uint4*)(whp);
      const uint4 b1 = *(const uint4*)(whp + 8);
      const uint4 c0 = *(const uint4*)(wlp);
      const uint4 c1 = *(const uint4*)(wlp + 8);
      whp += 32; wlp += 32;
      *(uint4*)&Bh[sA]     = b0;
      *(uint4*)&Bh[sA + 8] = b1;
      *(uint4*)&Bl[sA]     = c0;
      *(uint4*)&Bl[sA + 8] = c1;
    }
    __syncthreads();

    // ---- fragments + MFMA ----
    short8v ahi[4], alo[4], bhi[4], blo[4];
    #pragma unroll
    for (int i = 0; i < 4; i++) {
      const int ra = (wm + i*16 + lr) * LSR + g8;
      const int rb = (wn + i*16 + lr) * LSR + g8;
      ahi[i] = *(const short8v*)&Ah[ra];
      alo[i] = *(const short8v*)&Al[ra];
      bhi[i] = *(const short8v*)&Bh[rb];
      blo[i] = *(const short8v*)&Bl[rb];
    }
    #pragma unroll
    for (int i = 0; i < 4; i++)
      #pragma unroll
      for (int j = 0; j < 4; j++) {
        acc[i][j] = __builtin_amdgcn_mfma_f32_16x16x32_bf16(ahi[i], bhi[j], acc[i][j], 0, 0, 0);
        acc[i][j] = __builtin_amdgcn_mfma_f32_16x16x32_bf16(ahi[i], blo[j], acc[i][j], 0, 0, 0);
        acc[i][j] = __builtin_amdgcn_mfma_f32_16x16x32_bf16(alo[i], bhi[j], acc[i][j], 0, 0, 0);
      }
    __syncthreads();
  }

  // ---- epilogue: C/D layout (16x16): col = lane&15, row = (lane>>4)*4 + reg ----
  #pragma unroll
  for (int i = 0; i < 4; i++) {
    const int row0 = m0 + wm + i*16 + ((lane >> 4) << 2);
    #pragma unroll
    for (int j = 0; j < 4; j++) {
      const int col = n0 + wn + j*16 + lr;
      const float bi = bias ? bias[col] : 0.f;
      const f32x4 v = acc[i][j];
      #pragma unroll
      for (int r = 0; r < 4; r++) {
        const size_t off = (size_t)(row0 + r) * N + col;
        float o = v[r] + bi;
        if (addm) o += addm[off];
        C[off] = o;
      }
    }
  }
}

// ---------------- small fp32 GEMM: 64x64 tile (used once, for M2) ----------------
template<int TRANSB>
__global__ __launch_bounds__(256) void gemm_tile(
    const float* __restrict__ A, const float* __restrict__ W,
    const float* __restrict__ bias, const float* __restrict__ addm,
    float* __restrict__ C, int M, int N, int Kd)
{
  __shared__ float As[16][68];
  __shared__ float Ws[16][68];
  const int tid = threadIdx.x;
  const int n0 = blockIdx.x * 64;
  const int m0 = blockIdx.y * 64;
  const int l16 = tid & 15, r16 = tid >> 4;
  const int tx = tid & 15, ty = tid >> 4;
  float acc[4][4] = {};
  for (int d0 = 0; d0 < Kd; d0 += 16) {
    #pragma unroll
    for (int i = 0; i < 4; i++)
      As[l16][r16 + 16*i] = A[(size_t)(m0 + r16 + 16*i) * Kd + (d0 + l16)];
    if (TRANSB) {
      #pragma unroll
      for (int i = 0; i < 4; i++)
        Ws[l16][r16 + 16*i] = W[(size_t)(n0 + r16 + 16*i) * Kd + (d0 + l16)];
    } else {
      const int nn = tid & 63, dq = tid >> 6;
      #pragma unroll
      for (int i = 0; i < 4; i++)
        Ws[dq + 4*i][nn] = W[(size_t)(d0 + dq + 4*i) * N + (n0 + nn)];
    }
    __syncthreads();
    #pragma unroll
    for (int dd = 0; dd < 16; dd++) {
      const float4 a4 = *(const float4*)&As[dd][ty*4];
      const float4 b4 = *(const float4*)&Ws[dd][tx*4];
      const float av[4] = {a4.x, a4.y, a4.z, a4.w};
      const float bv[4] = {b4.x, b4.y, b4.z, b4.w};
      #pragma unroll
      for (int i = 0; i < 4; i++)
        #pragma unroll
        for (int j = 0; j < 4; j++)
          acc[i][j] = fmaf(av[i], bv[j], acc[i][j]);
    }
    __syncthreads();
  }
  const int n = n0 + tx*4;
  float4 bi = make_float4(0.f, 0.f, 0.f, 0.f);
  if (bias) bi = *(const float4*)&bias[n];
  #pragma unroll
  for (int i = 0; i < 4; i++) {
    const int m = m0 + ty*4 + i;
    float4 o = make_float4(acc[i][0] + bi.x, acc[i][1] + bi.y,
                           acc[i][2] + bi.z, acc[i][3] + bi.w);
    if (addm) {
      const float4 q4 = *(const float4*)&addm[(size_t)m*N + n];
      o.x += q4.x; o.y += q4.y; o.z += q4.z; o.w += q4.w;
    }
    *(float4*)&C[(size_t)m*N + n] = o;
  }
}

// ---------------- b2 = bv @ Wo^T + bo ----------------
__global__ __launch_bounds__(256) void bias2_kernel(
    const float* __restrict__ Wo, const float* __restrict__ bv,
    const float* __restrict__ bo, float* __restrict__ b2)
{
  const int i = threadIdx.x;
  float s = 0.f;
  for (int hh = 0; hh < HH; hh++) s = fmaf(bv[hh], Wo[(size_t)i*HH + hh], s);
  b2[i] = s + bo[i];
}

// ---------------- attention: e=u.c/16, softmax, cbar ----------------
__global__ __launch_bounds__(256) void attn_kernel(
    const float* __restrict__ c, const float* __restrict__ u,
    float* __restrict__ cbar)
{
  const size_t b = blockIdx.x;
  const int t = threadIdx.x;
  __shared__ float cs[KK*(HH+1)];
  __shared__ float us[HH];
  __shared__ float red2[8][32];
  __shared__ float att[KK];
  const float* cb = c + b*KK*HH;
  for (int i = t; i < KK*HH; i += 256) cs[(i>>8)*257 + (i&255)] = cb[i];
  us[t] = u[b*HH + t];
  __syncthreads();
  const int k = t & 31, j = t >> 5;
  float p = 0.f;
  #pragma unroll
  for (int i = 0; i < 32; i++) { const int d = j*32 + i; p = fmaf(us[d], cs[k*257 + d], p); }
  red2[j][k] = p;
  __syncthreads();
  if (t < KK) {
    float ev = 0.f;
    #pragma unroll
    for (int jj = 0; jj < 8; jj++) ev += red2[jj][t];
    ev *= 0.0625f;
    float m = ev;
    #pragma unroll
    for (int off = 16; off > 0; off >>= 1) m = fmaxf(m, __shfl_xor(m, off, 32));
    const float ex = expf(ev - m);
    float s = ex;
    #pragma unroll
    for (int off = 16; off > 0; off >>= 1) s += __shfl_xor(s, off, 32);
    att[t] = ex / s;
  }
  __syncthreads();
  float acc = 0.f;
  #pragma unroll
  for (int k2 = 0; k2 < KK; k2++) acc = fmaf(att[k2], cs[k2*257 + t], acc);
  cbar[b*HH + t] = acc;
}

// ---------------- LayerNorm over H ----------------
__global__ __launch_bounds__(256) void ln_kernel(
    const float* __restrict__ X, const float* __restrict__ g,
    const float* __restrict__ bb, float* __restrict__ out)
{
  __shared__ float redw[4];
  const size_t row = blockIdx.x;
  const int t = threadIdx.x;
  const float x = X[row*HH + t];
  const float mu = blk_sum256(x, redw) * (1.f/HH);
  const float d = x - mu;
  const float var = blk_sum256(d*d, redw) * (1.f/HH);
  out[row*HH + t] = d / sqrtf(var + 1e-5f) * g[t] + bb[t];
}

// ---------------- rowwise l2norm (in place, 256 cols) ----------------
__global__ __launch_bounds__(256) void l2row_kernel(float* __restrict__ X)
{
  __shared__ float redw[4];
  const size_t row = blockIdx.x;
  const int t = threadIdx.x;
  const float x = X[row*HH + t];
  const float n2 = blk_sum256(x*x, redw);
  X[row*HH + t] = x / fmaxf(sqrtf(n2), 1e-12f);
}

// ---------------- dpp = l2norm(cn @ W_dpp^T), 8 rows/block ----------------
__global__ __launch_bounds__(256) void dpp_kernel(
    const float* __restrict__ cn, const float* __restrict__ Wd,
    float* __restrict__ dpp)
{
  __shared__ float wds[RR*(HH+1)];
  __shared__ float rows[8*(HH+1)];
  const int t = threadIdx.x;
  for (int i = t; i < RR*HH; i += 256) wds[(i>>8)*257 + (i&255)] = Wd[i];
  const size_t m0 = (size_t)blockIdx.x * 8;
  for (int i = t; i < 8*HH; i += 256)
    rows[(i>>8)*257 + (i&255)] = cn[(m0 + (i>>8))*HH + (i&255)];
  __syncthreads();
  const int mi = t >> 5, r = t & 31;
  float p = 0.f;
  for (int d = 0; d < HH; d++) p = fmaf(rows[mi*257 + d], wds[r*257 + d], p);
  float sq = p*p;
  #pragma unroll
  for (int off = 16; off > 0; off >>= 1) sq += __shfl_xor(sq, off, 32);
  const float sc = 1.f / fmaxf(sqrtf(sq), 1e-12f);
  dpp[(m0 + mi)*RR + r] = p * sc;
}

// ---------------- per-step ----------------
__global__ __launch_bounds__(256) void step_kernel(
    const float* __restrict__ h, const float* __restrict__ cn,
    const float* __restrict__ dpp, const float* __restrict__ se,
    const int* __restrict__ labels, const float* __restrict__ lam_in,
    float* __restrict__ logits, float* __restrict__ msim,
    float* __restrict__ chosen, const int step)
{
  __shared__ float hes[HH];
  __shared__ float cns[KK*(HH+1)];
  __shared__ float dps[KK*(RR+1)];
  __shared__ float red2[8][32];
  __shared__ float redw[4];
  const size_t b = blockIdx.x;
  const int t = threadIdx.x;
  const float* cnb = cn + b*KK*HH;
  const float* dpb = dpp + b*KK*RR;
  for (int i = t; i < KK*HH; i += 256) cns[(i>>8)*257 + (i&255)] = cnb[i];
  for (int i = t; i < KK*RR; i += 256) dps[(i>>5)*33 + (i&31)] = dpb[i];
  const float hv = h[b*HH + t] + se[step*HH + t];
  const float n2 = blk_sum256(hv*hv, redw);
  hes[t] = hv / fmaxf(sqrtf(n2), 1e-12f);
  __syncthreads();
  const int k = t & 31, j = t >> 5;
  float p = 0.f;
  #pragma unroll
  for (int i = 0; i < 32; i++) { const int d = j*32 + i; p = fmaf(hes[d], cns[k*257 + d], p); }
  red2[j][k] = p;
  __syncthreads();
  if (t < KK) {
    float base = 0.f;
    #pragma unroll
    for (int jj = 0; jj < 8; jj++) base += red2[jj][t];
    float sc = base * 10.0f;
    if (step > 0) {
      const float x = lam_in[0];
      const float lam = (x > 0.f) ? (x + log1pf(expf(-x))) : log1pf(expf(x));
      const float ms = msim[b*KK + t];
      sc += lam * logf(1e-6f + 1.f - fminf(ms*ms, 0.999f));
    }
    for (int js = 0; js < step; js++)
      if (labels[b*SS + js] == t) sc = -100.f;
    logits[(b*SS + step)*KK + t] = sc;
  }
  if (step < SS - 1) {
    const int idx = labels[b*SS + step];
    chosen[b*HH + t] = cns[idx*257 + t];
    __syncthreads();
    if (t < KK) {
      float dn = 0.f;
      #pragma unroll
      for (int r = 0; r < RR; r++) dn = fmaf(dps[t*33 + r], dps[idx*33 + r], dn);
      const float old = (step == 0) ? -1e30f : msim[b*KK + t];
      msim[b*KK + t] = fmaxf(old, dn);
    }
  }
}

// ---------------- GRU combine + l2norm ----------------
__global__ __launch_bounds__(256) void gru_kernel(
    const float* __restrict__ gi, const float* __restrict__ gh,
    float* __restrict__ h)
{
  __shared__ float redw[4];
  const size_t b = blockIdx.x;
  const int t = threadIdx.x;
  const size_t g0 = b * (size_t)(3*HH);
  const float ir = gi[g0 + t], iz = gi[g0 + HH + t], inn = gi[g0 + 2*HH + t];
  const float hr = gh[g0 + t], hz = gh[g0 + HH + t], hn  = gh[g0 + 2*HH + t];
  const float r = 1.f / (1.f + expf(-(ir + hr)));
  const float z = 1.f / (1.f + expf(-(iz + hz)));
  const float n = tanhf(inn + r * hn);
  const float hv = h[b*HH + t];
  const float o = (1.f - z) * n + z * hv;
  const float n2 = blk_sum256(o*o, redw);
  h[b*HH + t] = o / fmaxf(sqrtf(n2), 1e-12f);
}

// ---------------- argmax + log-softmax loss ----------------
__global__ __launch_bounds__(256) void loss_kernel(
    const float* __restrict__ logits, const int* __restrict__ labels,
    float* __restrict__ preds, float* __restrict__ loss)
{
  const int i = blockIdx.x * 256 + threadIdx.x;
  const float* row = logits + (size_t)i * KK;
  float m = -1e30f; int arg = 0;
  #pragma unroll
  for (int k2 = 0; k2 < KK; k2++) {
    const float v = row[k2];
    if (v > m) { m = v; arg = k2; }
  }
  preds[i] = (float)arg;
  const float mx = fmaxf(m, -100.f);
  float se = 0.f, sl = 0.f;
  #pragma unroll
  for (int k2 = 0; k2 < KK; k2++) {
    const float li = fmaxf(row[k2], -100.f);
    se += expf(li - mx);
    sl += li;
  }
  const float lse = mx + logf(se);
  const int lab = labels[i];
  const float nll = lse - fmaxf(row[lab], -100.f);
  const float smooth = lse - sl * (1.f/KK);
  float contrib = (0.9f * nll + 0.1f * smooth) * (1.f / (BB*SS));
  #pragma unroll
  for (int off = 32; off > 0; off >>= 1) contrib += __shfl_down(contrib, off, 64);
  if ((threadIdx.x & 63) == 0) atomicAdd(loss, contrib);
}

// ---------------- launch ----------------
extern "C" void kernel_launch(void* const* d_in, const int* in_sizes, int n_in,
                              void* d_out, int out_size, void* d_ws, size_t ws_size,
                              hipStream_t stream)
{
  const float* query_emb  = (const float*)d_in[0];
  const float* cand_emb   = (const float*)d_in[1];
  const int*   labels     = (const int*)d_in[2];
  const float* W_in       = (const float*)d_in[3];
  const float* attn_in_w  = (const float*)d_in[4];
  const float* attn_in_b  = (const float*)d_in[5];
  const float* attn_out_w = (const float*)d_in[6];
  const float* attn_out_b = (const float*)d_in[7];
  const float* ln_g       = (const float*)d_in[8];
  const float* ln_b       = (const float*)d_in[9];
  const float* Wq         = (const float*)d_in[10];
  const float* Wc         = (const float*)d_in[11];
  const float* gru_wih    = (const float*)d_in[12];
  const float* gru_whh    = (const float*)d_in[13];
  const float* gru_bih    = (const float*)d_in[14];
  const float* gru_bhh    = (const float*)d_in[15];
  const float* step_emb   = (const float*)d_in[16];
  const float* W_dpp      = (const float*)d_in[17];
  const float* dpp_lam    = (const float*)d_in[18];

  float* out    = (float*)d_out;
  float* logits = out;
  float* preds  = out + (size_t)BB*SS*KK;
  float* loss   = preds + (size_t)BB*SS;

  float* wsf  = (float*)d_ws;
  float* c_   = wsf;
  float* cn_  = c_   + (size_t)BB*KK*HH;
  float* dpp_ = cn_  + (size_t)BB*KK*HH;
  float* q_   = dpp_ + (size_t)BB*KK*RR;
  float* bufA = q_   + (size_t)BB*HH;
  float* bufB = bufA + (size_t)BB*HH;
  float* bufC = bufB + (size_t)BB*HH;
  float* gi_  = bufC + (size_t)BB*HH;
  float* gh_  = gi_  + (size_t)BB*3*HH;
  float* ms_  = gh_  + (size_t)BB*3*HH;
  float* M2_  = ms_  + (size_t)BB*KK;
  float* b2_  = M2_  + (size_t)HH*HH;

  // bf16 hi/lo weight splits (all 16B-aligned: every count is a multiple of 8 u16)
  u16* sp      = (u16*)(b2_ + HH);
  u16* Win_hi  = sp;                  u16* Win_lo  = Win_hi + HH*DD;
  u16* Wqp_hi  = Win_lo + HH*DD;      u16* Wqp_lo  = Wqp_hi + HH*HH;
  u16* Wkt_hi  = Wqp_lo + HH*HH;      u16* Wkt_lo  = Wkt_hi + HH*HH;
  u16* M2_hi   = Wkt_lo + HH*HH;      u16* M2_lo   = M2_hi  + HH*HH;
  u16* Wq_hi   = M2_lo  + HH*HH;      u16* Wq_lo   = Wq_hi  + HH*HH;
  u16* Wc_hi   = Wq_lo  + HH*HH;      u16* Wc_lo   = Wc_hi  + HH*HH;
  u16* Wih_hi  = Wc_lo  + HH*HH;      u16* Wih_lo  = Wih_hi + 3*HH*HH;
  u16* Whh_hi  = Wih_lo + 3*HH*HH;    u16* Whh_lo  = Whh_hi + 3*HH*HH;

  hipMemsetAsync(loss, 0, sizeof(float), stream);

  const dim3 blk(256);

  // ---- weight prep (tiny) ----
  split_kernel<<<dim3((HH*DD+255)/256), blk, 0, stream>>>(W_in, Win_hi, Win_lo, HH*DD);
  split_kernel<<<dim3(HH*HH/256), blk, 0, stream>>>(attn_in_w, Wqp_hi, Wqp_lo, HH*HH);
  tsplit_kernel<<<dim3(HH*HH/256), blk, 0, stream>>>(attn_in_w + HH*HH, Wkt_hi, Wkt_lo, HH, HH);
  split_kernel<<<dim3(HH*HH/256), blk, 0, stream>>>(Wq, Wq_hi, Wq_lo, HH*HH);
  split_kernel<<<dim3(HH*HH/256), blk, 0, stream>>>(Wc, Wc_hi, Wc_lo, HH*HH);
  split_kernel<<<dim3(3*HH*HH/256), blk, 0, stream>>>(gru_wih, Wih_hi, Wih_lo, 3*HH*HH);
  split_kernel<<<dim3(3*HH*HH/256), blk, 0, stream>>>(gru_whh, Whh_hi, Whh_lo, 3*HH*HH);

  // M2 = Wo @ Wvp ; b2 = bv@Wo^T + bo ; split M2
  gemm_tile<0><<<dim3(4, 4), blk, 0, stream>>>(attn_out_w, attn_in_w + 512*HH,
                                               nullptr, nullptr, M2_, HH, HH, HH);
  bias2_kernel<<<1, blk, 0, stream>>>(attn_out_w, attn_in_b + 2*HH, attn_out_b, b2_);
  split_kernel<<<dim3(HH*HH/256), blk, 0, stream>>>(M2_, M2_hi, M2_lo, HH*HH);

  // q = query_emb @ W_in^T ; c = cand_emb @ W_in^T
  gemm_mfma<<<dim3(2, BB/128), blk, 0, stream>>>(query_emb, Win_hi, Win_lo,
                                                 nullptr, nullptr, q_, BB, HH, DD);
  gemm_mfma<<<dim3(2, BB*KK/128), blk, 0, stream>>>(cand_emb, Win_hi, Win_lo,
                                                    nullptr, nullptr, c_, BB*KK, HH, DD);
  // qh = q @ Wqp^T + bq ; u = qh @ Wkp
  gemm_mfma<<<dim3(2, BB/128), blk, 0, stream>>>(q_, Wqp_hi, Wqp_lo,
                                                 attn_in_b, nullptr, bufA, BB, HH, HH);
  gemm_mfma<<<dim3(2, BB/128), blk, 0, stream>>>(bufA, Wkt_hi, Wkt_lo,
                                                 nullptr, nullptr, bufB, BB, HH, HH);
  attn_kernel<<<BB, blk, 0, stream>>>(c_, bufB, bufA);
  // x = cbar @ M2^T + b2 + q
  gemm_mfma<<<dim3(2, BB/128), blk, 0, stream>>>(bufA, M2_hi, M2_lo,
                                                 b2_, q_, bufB, BB, HH, HH);
  ln_kernel<<<BB, blk, 0, stream>>>(bufB, ln_g, ln_b, bufA);
  // h = l2norm(enh @ Wq^T)
  gemm_mfma<<<dim3(2, BB/128), blk, 0, stream>>>(bufA, Wq_hi, Wq_lo,
                                                 nullptr, nullptr, bufB, BB, HH, HH);
  l2row_kernel<<<BB, blk, 0, stream>>>(bufB);
  // cand_n = l2norm(c @ Wc^T) ; dpp = l2norm(cand_n @ W_dpp^T)
  gemm_mfma<<<dim3(2, BB*KK/128), blk, 0, stream>>>(c_, Wc_hi, Wc_lo,
                                                    nullptr, nullptr, cn_, BB*KK, HH, HH);
  l2row_kernel<<<BB*KK, blk, 0, stream>>>(cn_);
  dpp_kernel<<<BB*KK/8, blk, 0, stream>>>(cn_, W_dpp, dpp_);

  for (int step = 0; step < SS; step++) {
    step_kernel<<<BB, blk, 0, stream>>>(bufB, cn_, dpp_, step_emb, labels, dpp_lam,
                                        logits, ms_, bufC, step);
    if (step < SS - 1) {
      gemm_mfma<<<dim3(6, BB/128), blk, 0, stream>>>(bufC, Wih_hi, Wih_lo,
                                                     gru_bih, nullptr, gi_, BB, 3*HH, HH);
      gemm_mfma<<<dim3(6, BB/128), blk, 0, stream>>>(bufB, Whh_hi, Whh_lo,
                                                     gru_bhh, nullptr, gh_, BB, 3*HH, HH);
      gru_kernel<<<BB, blk, 0, stream>>>(gi_, gh_, bufB);
    }
  }
  loss_kernel<<<BB*SS/256, blk, 0, stream>>>(logits, labels, preds, loss);
}

// Round 2
// 2523.243 us; speedup vs baseline: 1.4778x; 1.0946x over previous
//
#include <hip/hip_runtime.h>
#include <math.h>

#define BB 8192
#define KK 32
#define DD 768
#define HH 256
#define RR 32
#define SS 4

typedef unsigned short u16;
typedef unsigned int   u32;
typedef __attribute__((ext_vector_type(8))) short short8v;  // 8 bf16 (4 VGPRs)
typedef __attribute__((ext_vector_type(4))) float f32x4;

// ---------------- helpers ----------------
__device__ __forceinline__ float blk_sum256(float v, float* redw) {
  #pragma unroll
  for (int off = 32; off > 0; off >>= 1) v += __shfl_down(v, off, 64);
  __syncthreads();
  if ((threadIdx.x & 63) == 0) redw[threadIdx.x >> 6] = v;
  __syncthreads();
  return redw[0] + redw[1] + redw[2] + redw[3];
}

__device__ __forceinline__ u16 f2bf_rne(float f) {
  const u32 u = __float_as_uint(f);
  return (u16)((u + 0x7fffu + ((u >> 16) & 1u)) >> 16);
}

// async global->LDS, 16B per lane; dst is wave-uniform base, lane i lands at dst+16*i
__device__ __forceinline__ void gload16(const u16* g, u16* l) {
  __builtin_amdgcn_global_load_lds(
      (const __attribute__((address_space(1))) u32*)g,
      (__attribute__((address_space(3))) u32*)l, 16, 0, 0);
}

// ---------------- weight split: fp32 -> bf16 hi/lo ----------------
__global__ __launch_bounds__(256) void split_kernel(
    const float* __restrict__ W, u16* __restrict__ hi, u16* __restrict__ lo, int total)
{
  const int i = blockIdx.x * 256 + threadIdx.x;
  if (i < total) {
    const float f = W[i];
    const u32 u = __float_as_uint(f);
    hi[i] = (u16)(u >> 16);
    const float l = f - __uint_as_float(u & 0xffff0000u);
    lo[i] = f2bf_rne(l);
  }
}

// transpose-split: W[Rr][Cc] -> out[Cc][Rr] bf16 hi/lo
__global__ __launch_bounds__(256) void tsplit_kernel(
    const float* __restrict__ W, u16* __restrict__ hi, u16* __restrict__ lo, int Rr, int Cc)
{
  const int o = blockIdx.x * 256 + threadIdx.x;
  if (o < Rr * Cc) {
    const int c = o / Rr, r = o % Rr;
    const float f = W[(size_t)r * Cc + c];
    const u32 u = __float_as_uint(f);
    hi[o] = (u16)(u >> 16);
    const float l = f - __uint_as_float(u & 0xffff0000u);
    lo[o] = f2bf_rne(l);
  }
}

// ---------------- split-bf16 MFMA GEMM ----------------
// C[M,N] = A[M,Kd] @ W^T, W pre-split bf16 hi/lo, layout [N][Kd].
// ASPLIT: A pre-split bf16 hi/lo (Agh/Agl), staged via global_load_lds (no VALU).
// CSPLIT: write C as split bf16 (Chi/Clo) instead of fp32.
// rowss!=null: atomically accumulate per-row sum(C^2) (for fused l2norm).
// LDS: linear 64B rows, 16B-slot swizzle slot(r,b)=4r+(b^((r>>1)&3)):
//   conversion stores AND fragment reads hit all-distinct start banks per 8-lane group.
__global__ __launch_bounds__(256)
void __attribute__((noinline)) dummy_anchor() {}  // keep symbol ordering stable

template<int ASPLIT, int CSPLIT>
__global__ __launch_bounds__(256) void gemm_mfma(
    const float* __restrict__ A,
    const u16* __restrict__ Agh, const u16* __restrict__ Agl,
    const u16* __restrict__ Whi, const u16* __restrict__ Wlo,
    const float* __restrict__ bias, const float* __restrict__ addm,
    float* __restrict__ C, u16* __restrict__ Chi, u16* __restrict__ Clo,
    float* __restrict__ rowss,
    int M, int N, int Kd)
{
  __shared__ __align__(16) u16 Ah[128 * 32];
  __shared__ __align__(16) u16 Al[128 * 32];
  __shared__ __align__(16) u16 Bh[128 * 32];
  __shared__ __align__(16) u16 Bl[128 * 32];

  const int tid = threadIdx.x;
  // bijective XCD swizzle (all grids have nwg % 8 == 0)
  const int nbx = gridDim.x;
  const int nwg = nbx * gridDim.y;
  const int orig = blockIdx.y * nbx + blockIdx.x;
  const int wg = (orig & 7) * (nwg >> 3) + (orig >> 3);
  const int n0 = (wg % nbx) * 128;
  const int m0 = (wg / nbx) * 128;

  const int lane = tid & 63;
  const int w = tid >> 6;

  // gload_lds lane constants (B always; A when ASPLIT):
  const int grow = lane >> 2;                       // row within 16-row chunk
  const int gblk = (lane & 3) ^ ((lane >> 3) & 3);  // pre-swizzled global 16B block

  // A conversion-staging constants (non-ASPLIT)
  const int srow = tid >> 1;
  const int skq  = tid & 1;
  const int sx   = (srow >> 1) & 3;
  const int sa0  = srow * 32 + (((skq << 1)    ) ^ sx) * 8;
  const int sa1  = srow * 32 + (((skq << 1) | 1) ^ sx) * 8;
  const float* aptr = nullptr;
  if (!ASPLIT) aptr = &A[(size_t)(m0 + srow) * Kd + skq * 16];

  // compute-role constants
  const int lr = lane & 15;
  const int bx = (lane >> 4) ^ ((lr >> 1) & 3);
  const int roff = lr * 32 + bx * 8;
  const int wm = (w >> 1) << 6;
  const int wn = (w & 1) << 6;

  f32x4 acc[4][4] = {};

  for (int k0 = 0; k0 < Kd; k0 += 32) {
    // ---- B stage: async DMA, pre-swizzled global source, linear LDS dest ----
    #pragma unroll
    for (int cc = 0; cc < 2; cc++) {
      const size_t go = (size_t)(n0 + w*32 + cc*16 + grow) * Kd + k0 + 8*gblk;
      const int lo_ = (w*128 + cc*64) * 8;
      gload16(&Whi[go], &Bh[lo_]);
      gload16(&Wlo[go], &Bl[lo_]);
    }
    // ---- A stage ----
    if (ASPLIT) {
      #pragma unroll
      for (int cc = 0; cc < 2; cc++) {
        const size_t go = (size_t)(m0 + w*32 + cc*16 + grow) * Kd + k0 + 8*gblk;
        const int lo_ = (w*128 + cc*64) * 8;
        gload16(&Agh[go], &Ah[lo_]);
        gload16(&Agl[go], &Al[lo_]);
      }
    } else {
      float f[16];
      *(float4*)&f[0]  = *(const float4*)(aptr);
      *(float4*)&f[4]  = *(const float4*)(aptr + 4);
      *(float4*)&f[8]  = *(const float4*)(aptr + 8);
      *(float4*)&f[12] = *(const float4*)(aptr + 12);
      aptr += 32;
      u32 hp[8], lp[8];
      #pragma unroll
      for (int i = 0; i < 8; i++) {
        const u32 u0 = __float_as_uint(f[2*i]);
        const u32 u1 = __float_as_uint(f[2*i+1]);
        hp[i] = (u0 >> 16) | (u1 & 0xffff0000u);
        const float l0 = f[2*i]   - __uint_as_float(u0 & 0xffff0000u);
        const float l1 = f[2*i+1] - __uint_as_float(u1 & 0xffff0000u);
        lp[i] = (u32)f2bf_rne(l0) | ((u32)f2bf_rne(l1) << 16);
      }
      *(uint4*)&Ah[sa0] = make_uint4(hp[0], hp[1], hp[2], hp[3]);
      *(uint4*)&Ah[sa1] = make_uint4(hp[4], hp[5], hp[6], hp[7]);
      *(uint4*)&Al[sa0] = make_uint4(lp[0], lp[1], lp[2], lp[3]);
      *(uint4*)&Al[sa1] = make_uint4(lp[4], lp[5], lp[6], lp[7]);
    }
    __syncthreads();

    // ---- fragments + MFMA ----
    short8v ahi[4], alo[4], bhi[4], blo[4];
    #pragma unroll
    for (int i = 0; i < 4; i++) {
      const int ra = (wm + i*16) * 32 + roff;
      const int rb = (wn + i*16) * 32 + roff;
      ahi[i] = *(const short8v*)&Ah[ra];
      alo[i] = *(const short8v*)&Al[ra];
      bhi[i] = *(const short8v*)&Bh[rb];
      blo[i] = *(const short8v*)&Bl[rb];
    }
    #pragma unroll
    for (int i = 0; i < 4; i++)
      #pragma unroll
      for (int j = 0; j < 4; j++) {
        acc[i][j] = __builtin_amdgcn_mfma_f32_16x16x32_bf16(ahi[i], bhi[j], acc[i][j], 0, 0, 0);
        acc[i][j] = __builtin_amdgcn_mfma_f32_16x16x32_bf16(ahi[i], blo[j], acc[i][j], 0, 0, 0);
        acc[i][j] = __builtin_amdgcn_mfma_f32_16x16x32_bf16(alo[i], bhi[j], acc[i][j], 0, 0, 0);
      }
    __syncthreads();
  }

  // ---- epilogue: C/D 16x16 layout: col = lane&15, row = (lane>>4)*4 + reg ----
  #pragma unroll
  for (int i = 0; i < 4; i++) {
    const int row0 = m0 + wm + i*16 + ((lane >> 4) << 2);
    #pragma unroll
    for (int j = 0; j < 4; j++) {
      const int col = n0 + wn + j*16 + lr;
      const f32x4 v = acc[i][j];
      if (CSPLIT) {
        #pragma unroll
        for (int r = 0; r < 4; r++) {
          const size_t off = (size_t)(row0 + r) * N + col;
          const u32 u = __float_as_uint(v[r]);
          Chi[off] = (u16)(u >> 16);
          Clo[off] = f2bf_rne(v[r] - __uint_as_float(u & 0xffff0000u));
        }
      } else {
        const float bi = bias ? bias[col] : 0.f;
        #pragma unroll
        for (int r = 0; r < 4; r++) {
          const size_t off = (size_t)(row0 + r) * N + col;
          float o = v[r] + bi;
          if (addm) o += addm[off];
          C[off] = o;
        }
      }
    }
    if (rowss) {
      #pragma unroll
      for (int r = 0; r < 4; r++) {
        float ss = 0.f;
        #pragma unroll
        for (int j = 0; j < 4; j++) { const float vv = acc[i][j][r]; ss = fmaf(vv, vv, ss); }
        ss += __shfl_xor(ss, 8, 64);
        ss += __shfl_xor(ss, 4, 64);
        ss += __shfl_xor(ss, 2, 64);
        ss += __shfl_xor(ss, 1, 64);
        if (lr == 0) atomicAdd(&rowss[row0 + r], ss);
      }
    }
  }
}

// ---------------- rowss -> 1/max(sqrt(ss),eps) ----------------
__global__ __launch_bounds__(256) void rsq_kernel(float* __restrict__ x)
{
  const int i = blockIdx.x * 256 + threadIdx.x;
  x[i] = 1.f / fmaxf(sqrtf(x[i]), 1e-12f);
}

// ---------------- small fp32 GEMM: 64x64 tile (used once, for M2) ----------------
template<int TRANSB>
__global__ __launch_bounds__(256) void gemm_tile(
    const float* __restrict__ A, const float* __restrict__ W,
    const float* __restrict__ bias, const float* __restrict__ addm,
    float* __restrict__ C, int M, int N, int Kd)
{
  __shared__ float As[16][68];
  __shared__ float Ws[16][68];
  const int tid = threadIdx.x;
  const int n0 = blockIdx.x * 64;
  const int m0 = blockIdx.y * 64;
  const int l16 = tid & 15, r16 = tid >> 4;
  const int tx = tid & 15, ty = tid >> 4;
  float acc[4][4] = {};
  for (int d0 = 0; d0 < Kd; d0 += 16) {
    #pragma unroll
    for (int i = 0; i < 4; i++)
      As[l16][r16 + 16*i] = A[(size_t)(m0 + r16 + 16*i) * Kd + (d0 + l16)];
    if (TRANSB) {
      #pragma unroll
      for (int i = 0; i < 4; i++)
        Ws[l16][r16 + 16*i] = W[(size_t)(n0 + r16 + 16*i) * Kd + (d0 + l16)];
    } else {
      const int nn = tid & 63, dq = tid >> 6;
      #pragma unroll
      for (int i = 0; i < 4; i++)
        Ws[dq + 4*i][nn] = W[(size_t)(d0 + dq + 4*i) * N + (n0 + nn)];
    }
    __syncthreads();
    #pragma unroll
    for (int dd = 0; dd < 16; dd++) {
      const float4 a4 = *(const float4*)&As[dd][ty*4];
      const float4 b4 = *(const float4*)&Ws[dd][tx*4];
      const float av[4] = {a4.x, a4.y, a4.z, a4.w};
      const float bv[4] = {b4.x, b4.y, b4.z, b4.w};
      #pragma unroll
      for (int i = 0; i < 4; i++)
        #pragma unroll
        for (int j = 0; j < 4; j++)
          acc[i][j] = fmaf(av[i], bv[j], acc[i][j]);
    }
    __syncthreads();
  }
  const int n = n0 + tx*4;
  float4 bi = make_float4(0.f, 0.f, 0.f, 0.f);
  if (bias) bi = *(const float4*)&bias[n];
  #pragma unroll
  for (int i = 0; i < 4; i++) {
    const int m = m0 + ty*4 + i;
    float4 o = make_float4(acc[i][0] + bi.x, acc[i][1] + bi.y,
                           acc[i][2] + bi.z, acc[i][3] + bi.w);
    if (addm) {
      const float4 q4 = *(const float4*)&addm[(size_t)m*N + n];
      o.x += q4.x; o.y += q4.y; o.z += q4.z; o.w += q4.w;
    }
    *(float4*)&C[(size_t)m*N + n] = o;
  }
}

// ---------------- b2 = bv @ Wo^T + bo ----------------
__global__ __launch_bounds__(256) void bias2_kernel(
    const float* __restrict__ Wo, const float* __restrict__ bv,
    const float* __restrict__ bo, float* __restrict__ b2)
{
  const int i = threadIdx.x;
  float s = 0.f;
  for (int hh = 0; hh < HH; hh++) s = fmaf(bv[hh], Wo[(size_t)i*HH + hh], s);
  b2[i] = s + bo[i];
}

// ---------------- attention: e=u.c/16, softmax, cbar (c from split bf16) ----------------
__global__ __launch_bounds__(256) void attn_kernel(
    const u16* __restrict__ chi, const u16* __restrict__ clo,
    const float* __restrict__ u, float* __restrict__ cbar)
{
  const size_t b = blockIdx.x;
  const int t = threadIdx.x;
  __shared__ float cs[KK*(HH+1)];
  __shared__ float us[HH];
  __shared__ float red2[8][32];
  __shared__ float att[KK];
  const u16* ch = chi + b*KK*HH;
  const u16* cl = clo + b*KK*HH;
  for (int i = t*2; i < KK*HH; i += 512) {
    const u32 h2 = *(const u32*)&ch[i];
    const u32 l2 = *(const u32*)&cl[i];
    const int row = i >> 8, c0 = i & 255;
    cs[row*257 + c0]     = __uint_as_float(h2 << 16) + __uint_as_float(l2 << 16);
    cs[row*257 + c0 + 1] = __uint_as_float(h2 & 0xffff0000u) + __uint_as_float(l2 & 0xffff0000u);
  }
  us[t] = u[b*HH + t];
  __syncthreads();
  const int k = t & 31, j = t >> 5;
  float p = 0.f;
  #pragma unroll
  for (int i = 0; i < 32; i++) { const int d = j*32 + i; p = fmaf(us[d], cs[k*257 + d], p); }
  red2[j][k] = p;
  __syncthreads();
  if (t < KK) {
    float ev = 0.f;
    #pragma unroll
    for (int jj = 0; jj < 8; jj++) ev += red2[jj][t];
    ev *= 0.0625f;
    float m = ev;
    #pragma unroll
    for (int off = 16; off > 0; off >>= 1) m = fmaxf(m, __shfl_xor(m, off, 32));
    const float ex = expf(ev - m);
    float s = ex;
    #pragma unroll
    for (int off = 16; off > 0; off >>= 1) s += __shfl_xor(s, off, 32);
    att[t] = ex / s;
  }
  __syncthreads();
  float acc = 0.f;
  #pragma unroll
  for (int k2 = 0; k2 < KK; k2++) acc = fmaf(att[k2], cs[k2*257 + t], acc);
  cbar[b*HH + t] = acc;
}

// ---------------- LayerNorm over H ----------------
__global__ __launch_bounds__(256) void ln_kernel(
    const float* __restrict__ X, const float* __restrict__ g,
    const float* __restrict__ bb, float* __restrict__ out)
{
  __shared__ float redw[4];
  const size_t row = blockIdx.x;
  const int t = threadIdx.x;
  const float x = X[row*HH + t];
  const float mu = blk_sum256(x, redw) * (1.f/HH);
  const float d = x - mu;
  const float var = blk_sum256(d*d, redw) * (1.f/HH);
  out[row*HH + t] = d / sqrtf(var + 1e-5f) * g[t] + bb[t];
}

// ---------------- rowwise l2norm (in place, 256 cols) ----------------
__global__ __launch_bounds__(256) void l2row_kernel(float* __restrict__ X)
{
  __shared__ float redw[4];
  const size_t row = blockIdx.x;
  const int t = threadIdx.x;
  const float x = X[row*HH + t];
  const float n2 = blk_sum256(x*x, redw);
  X[row*HH + t] = x / fmaxf(sqrtf(n2), 1e-12f);
}

// ---------------- dpp = l2norm(cn @ W_dpp^T), 8 rows/block ----------------
// NOTE: cn here is UNnormalized; l2norm over R removes the positive row scale.
__global__ __launch_bounds__(256) void dpp_kernel(
    const float* __restrict__ cn, const float* __restrict__ Wd,
    float* __restrict__ dpp)
{
  __shared__ float wds[RR*(HH+1)];
  __shared__ float rows[8*(HH+1)];
  const int t = threadIdx.x;
  for (int i = t; i < RR*HH; i += 256) wds[(i>>8)*257 + (i&255)] = Wd[i];
  const size_t m0 = (size_t)blockIdx.x * 8;
  for (int i = t; i < 8*HH; i += 256)
    rows[(i>>8)*257 + (i&255)] = cn[(m0 + (i>>8))*HH + (i&255)];
  __syncthreads();
  const int mi = t >> 5, r = t & 31;
  float p = 0.f;
  for (int d = 0; d < HH; d++) p = fmaf(rows[mi*257 + d], wds[r*257 + d], p);
  float sq = p*p;
  #pragma unroll
  for (int off = 16; off > 0; off >>= 1) sq += __shfl_xor(sq, off, 32);
  const float sc = 1.f / fmaxf(sqrtf(sq), 1e-12f);
  dpp[(m0 + mi)*RR + r] = p * sc;
}

// ---------------- per-step (cn scaled by rs on load) ----------------
__global__ __launch_bounds__(256) void step_kernel(
    const float* __restrict__ h, const float* __restrict__ cn,
    const float* __restrict__ rs,
    const float* __restrict__ dpp, const float* __restrict__ se,
    const int* __restrict__ labels, const float* __restrict__ lam_in,
    float* __restrict__ logits, float* __restrict__ msim,
    float* __restrict__ chosen, const int step)
{
  __shared__ float hes[HH];
  __shared__ float cns[KK*(HH+1)];
  __shared__ float dps[KK*(RR+1)];
  __shared__ float red2[8][32];
  __shared__ float redw[4];
  const size_t b = blockIdx.x;
  const int t = threadIdx.x;
  const float* cnb = cn + b*KK*HH;
  const float* rsb = rs + b*KK;
  const float* dpb = dpp + b*KK*RR;
  for (int i = t; i < KK*HH; i += 256)
    cns[(i>>8)*257 + (i&255)] = cnb[i] * rsb[i>>8];
  for (int i = t; i < KK*RR; i += 256) dps[(i>>5)*33 + (i&31)] = dpb[i];
  const float hv = h[b*HH + t] + se[step*HH + t];
  const float n2 = blk_sum256(hv*hv, redw);
  hes[t] = hv / fmaxf(sqrtf(n2), 1e-12f);
  __syncthreads();
  const int k = t & 31, j = t >> 5;
  float p = 0.f;
  #pragma unroll
  for (int i = 0; i < 32; i++) { const int d = j*32 + i; p = fmaf(hes[d], cns[k*257 + d], p); }
  red2[j][k] = p;
  __syncthreads();
  if (t < KK) {
    float base = 0.f;
    #pragma unroll
    for (int jj = 0; jj < 8; jj++) base += red2[jj][t];
    float sc = base * 10.0f;
    if (step > 0) {
      const float x = lam_in[0];
      const float lam = (x > 0.f) ? (x + log1pf(expf(-x))) : log1pf(expf(x));
      const float ms = msim[b*KK + t];
      sc += lam * logf(1e-6f + 1.f - fminf(ms*ms, 0.999f));
    }
    for (int js = 0; js < step; js++)
      if (labels[b*SS + js] == t) sc = -100.f;
    logits[(b*SS + step)*KK + t] = sc;
  }
  if (step < SS - 1) {
    const int idx = labels[b*SS + step];
    chosen[b*HH + t] = cns[idx*257 + t];
    __syncthreads();
    if (t < KK) {
      float dn = 0.f;
      #pragma unroll
      for (int r = 0; r < RR; r++) dn = fmaf(dps[t*33 + r], dps[idx*33 + r], dn);
      const float old = (step == 0) ? -1e30f : msim[b*KK + t];
      msim[b*KK + t] = fmaxf(old, dn);
    }
  }
}

// ---------------- GRU combine + l2norm ----------------
__global__ __launch_bounds__(256) void gru_kernel(
    const float* __restrict__ gi, const float* __restrict__ gh,
    float* __restrict__ h)
{
  __shared__ float redw[4];
  const size_t b = blockIdx.x;
  const int t = threadIdx.x;
  const size_t g0 = b * (size_t)(3*HH);
  const float ir = gi[g0 + t], iz = gi[g0 + HH + t], inn = gi[g0 + 2*HH + t];
  const float hr = gh[g0 + t], hz = gh[g0 + HH + t], hn  = gh[g0 + 2*HH + t];
  const float r = 1.f / (1.f + expf(-(ir + hr)));
  const float z = 1.f / (1.f + expf(-(iz + hz)));
  const float n = tanhf(inn + r * hn);
  const float hv = h[b*HH + t];
  const float o = (1.f - z) * n + z * hv;
  const float n2 = blk_sum256(o*o, redw);
  h[b*HH + t] = o / fmaxf(sqrtf(n2), 1e-12f);
}

// ---------------- argmax + log-softmax loss ----------------
__global__ __launch_bounds__(256) void loss_kernel(
    const float* __restrict__ logits, const int* __restrict__ labels,
    float* __restrict__ preds, float* __restrict__ loss)
{
  const int i = blockIdx.x * 256 + threadIdx.x;
  const float* row = logits + (size_t)i * KK;
  float m = -1e30f; int arg = 0;
  #pragma unroll
  for (int k2 = 0; k2 < KK; k2++) {
    const float v = row[k2];
    if (v > m) { m = v; arg = k2; }
  }
  preds[i] = (float)arg;
  const float mx = fmaxf(m, -100.f);
  float se = 0.f, sl = 0.f;
  #pragma unroll
  for (int k2 = 0; k2 < KK; k2++) {
    const float li = fmaxf(row[k2], -100.f);
    se += expf(li - mx);
    sl += li;
  }
  const float lse = mx + logf(se);
  const int lab = labels[i];
  const float nll = lse - fmaxf(row[lab], -100.f);
  const float smooth = lse - sl * (1.f/KK);
  float contrib = (0.9f * nll + 0.1f * smooth) * (1.f / (BB*SS));
  #pragma unroll
  for (int off = 32; off > 0; off >>= 1) contrib += __shfl_down(contrib, off, 64);
  if ((threadIdx.x & 63) == 0) atomicAdd(loss, contrib);
}

// ---------------- launch ----------------
extern "C" void kernel_launch(void* const* d_in, const int* in_sizes, int n_in,
                              void* d_out, int out_size, void* d_ws, size_t ws_size,
                              hipStream_t stream)
{
  const float* query_emb  = (const float*)d_in[0];
  const float* cand_emb   = (const float*)d_in[1];
  const int*   labels     = (const int*)d_in[2];
  const float* W_in       = (const float*)d_in[3];
  const float* attn_in_w  = (const float*)d_in[4];
  const float* attn_in_b  = (const float*)d_in[5];
  const float* attn_out_w = (const float*)d_in[6];
  const float* attn_out_b = (const float*)d_in[7];
  const float* ln_g       = (const float*)d_in[8];
  const float* ln_b       = (const float*)d_in[9];
  const float* Wq         = (const float*)d_in[10];
  const float* Wc         = (const float*)d_in[11];
  const float* gru_wih    = (const float*)d_in[12];
  const float* gru_whh    = (const float*)d_in[13];
  const float* gru_bih    = (const float*)d_in[14];
  const float* gru_bhh    = (const float*)d_in[15];
  const float* step_emb   = (const float*)d_in[16];
  const float* W_dpp      = (const float*)d_in[17];
  const float* dpp_lam    = (const float*)d_in[18];

  float* out    = (float*)d_out;
  float* logits = out;
  float* preds  = out + (size_t)BB*SS*KK;
  float* loss   = preds + (size_t)BB*SS;

  float* wsf  = (float*)d_ws;
  float* cn_  = wsf;
  float* dpp_ = cn_  + (size_t)BB*KK*HH;
  float* q_   = dpp_ + (size_t)BB*KK*RR;
  float* bufA = q_   + (size_t)BB*HH;
  float* bufB = bufA + (size_t)BB*HH;
  float* bufC = bufB + (size_t)BB*HH;
  float* gi_  = bufC + (size_t)BB*HH;
  float* gh_  = gi_  + (size_t)BB*3*HH;
  float* ms_  = gh_  + (size_t)BB*3*HH;
  float* rs_  = ms_  + (size_t)BB*KK;
  float* M2_  = rs_  + (size_t)BB*KK;
  float* b2_  = M2_  + (size_t)HH*HH;

  // c stored only as split bf16 (same bytes as fp32 c)
  u16* c_hi   = (u16*)(b2_ + HH);
  u16* c_lo   = c_hi + (size_t)BB*KK*HH;
  u16* sp     = c_lo + (size_t)BB*KK*HH;
  u16* Win_hi = sp;                  u16* Win_lo = Win_hi + HH*DD;
  u16* Wqp_hi = Win_lo + HH*DD;      u16* Wqp_lo = Wqp_hi + HH*HH;
  u16* Wkt_hi = Wqp_lo + HH*HH;      u16* Wkt_lo = Wkt_hi + HH*HH;
  u16* M2_hi  = Wkt_lo + HH*HH;      u16* M2_lo  = M2_hi  + HH*HH;
  u16* Wq_hi  = M2_lo  + HH*HH;      u16* Wq_lo  = Wq_hi  + HH*HH;
  u16* Wc_hi  = Wq_lo  + HH*HH;      u16* Wc_lo  = Wc_hi  + HH*HH;
  u16* Wih_hi = Wc_lo  + HH*HH;      u16* Wih_lo = Wih_hi + 3*HH*HH;
  u16* Whh_hi = Wih_lo + 3*HH*HH;    u16* Whh_lo = Whh_hi + 3*HH*HH;

  hipMemsetAsync(loss, 0, sizeof(float), stream);
  hipMemsetAsync(rs_, 0, (size_t)BB*KK*sizeof(float), stream);

  const dim3 blk(256);

  // ---- weight prep (tiny) ----
  split_kernel<<<dim3((HH*DD+255)/256), blk, 0, stream>>>(W_in, Win_hi, Win_lo, HH*DD);
  split_kernel<<<dim3(HH*HH/256), blk, 0, stream>>>(attn_in_w, Wqp_hi, Wqp_lo, HH*HH);
  tsplit_kernel<<<dim3(HH*HH/256), blk, 0, stream>>>(attn_in_w + HH*HH, Wkt_hi, Wkt_lo, HH, HH);
  split_kernel<<<dim3(HH*HH/256), blk, 0, stream>>>(Wq, Wq_hi, Wq_lo, HH*HH);
  split_kernel<<<dim3(HH*HH/256), blk, 0, stream>>>(Wc, Wc_hi, Wc_lo, HH*HH);
  split_kernel<<<dim3(3*HH*HH/256), blk, 0, stream>>>(gru_wih, Wih_hi, Wih_lo, 3*HH*HH);
  split_kernel<<<dim3(3*HH*HH/256), blk, 0, stream>>>(gru_whh, Whh_hi, Whh_lo, 3*HH*HH);

  // M2 = Wo @ Wvp ; b2 = bv@Wo^T + bo ; split M2
  gemm_tile<0><<<dim3(4, 4), blk, 0, stream>>>(attn_out_w, attn_in_w + 512*HH,
                                               nullptr, nullptr, M2_, HH, HH, HH);
  bias2_kernel<<<1, blk, 0, stream>>>(attn_out_w, attn_in_b + 2*HH, attn_out_b, b2_);
  split_kernel<<<dim3(HH*HH/256), blk, 0, stream>>>(M2_, M2_hi, M2_lo, HH*HH);

  // q = query_emb @ W_in^T ; c = cand_emb @ W_in^T (c written as split bf16)
  gemm_mfma<0,0><<<dim3(2, BB/128), blk, 0, stream>>>(query_emb, nullptr, nullptr,
      Win_hi, Win_lo, nullptr, nullptr, q_, nullptr, nullptr, nullptr, BB, HH, DD);
  gemm_mfma<0,1><<<dim3(2, BB*KK/128), blk, 0, stream>>>(cand_emb, nullptr, nullptr,
      Win_hi, Win_lo, nullptr, nullptr, nullptr, c_hi, c_lo, nullptr, BB*KK, HH, DD);

  // qh = q @ Wqp^T + bq ; u = qh @ Wkp
  gemm_mfma<0,0><<<dim3(2, BB/128), blk, 0, stream>>>(q_, nullptr, nullptr,
      Wqp_hi, Wqp_lo, attn_in_b, nullptr, bufA, nullptr, nullptr, nullptr, BB, HH, HH);
  gemm_mfma<0,0><<<dim3(2, BB/128), blk, 0, stream>>>(bufA, nullptr, nullptr,
      Wkt_hi, Wkt_lo, nullptr, nullptr, bufB, nullptr, nullptr, nullptr, BB, HH, HH);
  attn_kernel<<<BB, blk, 0, stream>>>(c_hi, c_lo, bufB, bufA);
  // x = cbar @ M2^T + b2 + q
  gemm_mfma<0,0><<<dim3(2, BB/128), blk, 0, stream>>>(bufA, nullptr, nullptr,
      M2_hi, M2_lo, b2_, q_, bufB, nullptr, nullptr, nullptr, BB, HH, HH);
  ln_kernel<<<BB, blk, 0, stream>>>(bufB, ln_g, ln_b, bufA);
  // h = l2norm(enh @ Wq^T)
  gemm_mfma<0,0><<<dim3(2, BB/128), blk, 0, stream>>>(bufA, nullptr, nullptr,
      Wq_hi, Wq_lo, nullptr, nullptr, bufB, nullptr, nullptr, nullptr, BB, HH, HH);
  l2row_kernel<<<BB, blk, 0, stream>>>(bufB);

  // cand_n_unnorm = c @ Wc^T (A pre-split, fused rowwise sumsq) ; rs = 1/||row||
  gemm_mfma<1,0><<<dim3(2, BB*KK/128), blk, 0, stream>>>(nullptr, c_hi, c_lo,
      Wc_hi, Wc_lo, nullptr, nullptr, cn_, nullptr, nullptr, rs_, BB*KK, HH, HH);
  rsq_kernel<<<dim3(BB*KK/256), blk, 0, stream>>>(rs_);
  // dpp from unnormalized cn (l2norm removes the row scale)
  dpp_kernel<<<BB*KK/8, blk, 0, stream>>>(cn_, W_dpp, dpp_);

  for (int step = 0; step < SS; step++) {
    step_kernel<<<BB, blk, 0, stream>>>(bufB, cn_, rs_, dpp_, step_emb, labels, dpp_lam,
                                        logits, ms_, bufC, step);
    if (step < SS - 1) {
      gemm_mfma<0,0><<<dim3(6, BB/128), blk, 0, stream>>>(bufC, nullptr, nullptr,
          Wih_hi, Wih_lo, gru_bih, nullptr, gi_, nullptr, nullptr, nullptr, BB, 3*HH, HH);
      gemm_mfma<0,0><<<dim3(6, BB/128), blk, 0, stream>>>(bufB, nullptr, nullptr,
          Whh_hi, Whh_lo, gru_bhh, nullptr, gh_, nullptr, nullptr, nullptr, BB, 3*HH, HH);
      gru_kernel<<<BB, blk, 0, stream>>>(gi_, gh_, bufB);
    }
  }
  loss_kernel<<<BB*SS/256, blk, 0, stream>>>(logits, labels, preds, loss);
}